// Round 4
// baseline (420.690 us; speedup 1.0000x reference)
//
#include <hip/hip_runtime.h>

// GPT2 attention with soft-threshold pruning.
// Precision-critical scores use split-bf16 (hi+lo) MFMA: error ~2^-17 instead
// of 2^-9, because the soft-threshold w' = C + (w-C)*sigmoid(10w) amplifies
// score error by up to ~600x at softmax-weight-bearing entries.
// CRITICAL semantics: reference soft-thresholds AFTER masking, then softmaxes
// the FULL row. Masked entries sit at exactly C; when a row's max w' is within
// ~88 of C (all live scores < ~-0.47, happens for early rows), masked FUTURE
// keys contribute exp(C-m) > 0 and the reference attends (near-uniformly) to
// all 2048 keys. So the kv loop must cover all blocks, with a block-uniform
// early-exit once exp(C-m) underflows to 0 for every row (m - C > 100).
// Stages: qkv = hs@Wqkv+b   (split A, split W -> fp32 ws)
//         flash attn        (split QK^T, bf16 PV -> fp32 ws)
//         out = attn@Wproj+b(split A, bf16 W -> fp32 d_out)

#define S_LEN   2048
#define DMODEL  1024
#define NHEAD   16
#define HDIM    64
#define N_QKV   3072
#define SLOPE   10.0f
#define CMASK   -10000.0f
#define LDT     72      // LDS leading dim (shorts): 16B-aligned rows, 2-way max bank alias

typedef short s16x4 __attribute__((ext_vector_type(4)));
typedef short s16x8 __attribute__((ext_vector_type(8)));
typedef float f32x4 __attribute__((ext_vector_type(4)));

__device__ __forceinline__ short f2bf(float f) {
    unsigned u = __float_as_uint(f);
    u += 0x7fffu + ((u >> 16) & 1u);          // RNE
    return (short)(u >> 16);
}

struct bfpair { short hi, lo; };
__device__ __forceinline__ bfpair split_bf(float x) {
    bfpair r;
    r.hi = f2bf(x);
    float fh = __uint_as_float(((unsigned)(unsigned short)r.hi) << 16);
    r.lo = f2bf(x - fh);                      // x - fh exact
    return r;
}

// ---------------- GEMM: C[M,N] = A[M,K] @ W[K,N] + bias (fp32 out) --------
// A always fp32, split into hi/lo bf16.  W split iff WSPLIT (else bf16).
// 128x128 tile, BK=64, 4 waves (2x2 of 64x64), mfma 16x16x32 bf16.
template<int N, bool WSPLIT>
__global__ __launch_bounds__(256)
void gemm_split(const float* __restrict__ A, const float* __restrict__ W,
                const float* __restrict__ bias, float* __restrict__ C, int K)
{
    __shared__ __align__(16) short Ah[128 * LDT];   // [m][k] hi
    __shared__ __align__(16) short Al[128 * LDT];   // [m][k] lo
    __shared__ __align__(16) short Bh[128 * LDT];   // [n][k] hi (W transposed)
    __shared__ __align__(16) short Bl[WSPLIT ? 128 * LDT : 16];

    const int tid  = threadIdx.x;
    const int brow = blockIdx.y * 128, bcol = blockIdx.x * 128;
    const int lane = tid & 63, wid = tid >> 6;
    const int lr = lane & 15, lg = lane >> 4;
    const int wm = (wid >> 1) * 64, wn = (wid & 1) * 64;

    f32x4 acc[4][4];
#pragma unroll
    for (int m = 0; m < 4; ++m)
#pragma unroll
        for (int n = 0; n < 4; ++n) acc[m][n] = (f32x4){0.f, 0.f, 0.f, 0.f};

    for (int k0 = 0; k0 < K; k0 += 64) {
        // stage A tile [128 rows][64 k] -> hi/lo bf16
#pragma unroll
        for (int it = 0; it < 8; ++it) {
            int idx = tid + it * 256;               // 0..2047
            int r = idx >> 4, c4 = (idx & 15) * 4;
            float4 v = *(const float4*)&A[(size_t)(brow + r) * K + k0 + c4];
            bfpair px = split_bf(v.x), py = split_bf(v.y);
            bfpair pz = split_bf(v.z), pw = split_bf(v.w);
            s16x4 h, l;
            h.x = px.hi; h.y = py.hi; h.z = pz.hi; h.w = pw.hi;
            l.x = px.lo; l.y = py.lo; l.z = pz.lo; l.w = pw.lo;
            *(s16x4*)&Ah[r * LDT + c4] = h;
            *(s16x4*)&Al[r * LDT + c4] = l;
        }
        // stage W tile [64 k][128 n] transposed -> Bs[n][k]
#pragma unroll
        for (int it = 0; it < 8; ++it) {
            int idx = tid + it * 256;               // 0..2047
            int kk = idx >> 5, c4 = (idx & 31) * 4;
            float4 v = *(const float4*)&W[(size_t)(k0 + kk) * N + bcol + c4];
            if constexpr (WSPLIT) {
                bfpair p;
                p = split_bf(v.x); Bh[(c4+0)*LDT + kk] = p.hi; Bl[(c4+0)*LDT + kk] = p.lo;
                p = split_bf(v.y); Bh[(c4+1)*LDT + kk] = p.hi; Bl[(c4+1)*LDT + kk] = p.lo;
                p = split_bf(v.z); Bh[(c4+2)*LDT + kk] = p.hi; Bl[(c4+2)*LDT + kk] = p.lo;
                p = split_bf(v.w); Bh[(c4+3)*LDT + kk] = p.hi; Bl[(c4+3)*LDT + kk] = p.lo;
            } else {
                Bh[(c4+0)*LDT + kk] = f2bf(v.x);
                Bh[(c4+1)*LDT + kk] = f2bf(v.y);
                Bh[(c4+2)*LDT + kk] = f2bf(v.z);
                Bh[(c4+3)*LDT + kk] = f2bf(v.w);
            }
        }
        __syncthreads();

#pragma unroll
        for (int kc = 0; kc < 2; ++kc) {
            s16x8 ah[4], al[4], bh[4], bl[4];
#pragma unroll
            for (int m = 0; m < 4; ++m) {
                ah[m] = *(const s16x8*)&Ah[(wm + m * 16 + lr) * LDT + kc * 32 + lg * 8];
                al[m] = *(const s16x8*)&Al[(wm + m * 16 + lr) * LDT + kc * 32 + lg * 8];
            }
#pragma unroll
            for (int n = 0; n < 4; ++n) {
                bh[n] = *(const s16x8*)&Bh[(wn + n * 16 + lr) * LDT + kc * 32 + lg * 8];
                if constexpr (WSPLIT)
                    bl[n] = *(const s16x8*)&Bl[(wn + n * 16 + lr) * LDT + kc * 32 + lg * 8];
            }
#pragma unroll
            for (int m = 0; m < 4; ++m)
#pragma unroll
                for (int n = 0; n < 4; ++n) {
                    acc[m][n] = __builtin_amdgcn_mfma_f32_16x16x32_bf16(ah[m], bh[n], acc[m][n], 0, 0, 0);
                    if constexpr (WSPLIT)
                        acc[m][n] = __builtin_amdgcn_mfma_f32_16x16x32_bf16(ah[m], bl[n], acc[m][n], 0, 0, 0);
                    acc[m][n] = __builtin_amdgcn_mfma_f32_16x16x32_bf16(al[m], bh[n], acc[m][n], 0, 0, 0);
                }
        }
        __syncthreads();
    }

    // epilogue: D layout col=lane&15, row=(lane>>4)*4+v
#pragma unroll
    for (int m = 0; m < 4; ++m)
#pragma unroll
        for (int n = 0; n < 4; ++n) {
            int row = brow + wm + m * 16 + lg * 4;
            int col = bcol + wn + n * 16 + lr;
            float bv = bias[col];
#pragma unroll
            for (int v = 0; v < 4; ++v)
                C[(size_t)(row + v) * N + col] = acc[m][n][v] + bv;
        }
}

// ---------------- Flash attention with soft-threshold pruning ----------------
// grid: (S/64 q-blocks, H heads). 4 waves; wave w owns q rows [qb*64+w*16, +16).
// Q,K split hi/lo bf16 (score precision); V,P bf16; out fp32.
// kv loop covers ALL blocks (masked-future entries at exactly CMASK take part
// in softmax like the reference); block-uniform break once exp(C-m)==0 f32.
__global__ __launch_bounds__(256)
void attn_fwd(const float* __restrict__ qkv, float* __restrict__ attn_out)
{
    __shared__ __align__(16) short Qh[64 * LDT], Ql[64 * LDT];
    __shared__ __align__(16) short Kh[64 * LDT], Kl[64 * LDT];
    __shared__ __align__(16) short VTs[64 * LDT];   // V transposed: [hd][key]
    __shared__ __align__(16) short Ps[4][16 * LDT]; // per-wave P tile [qrow][key]

    const int qb = blockIdx.x, h = blockIdx.y;
    const int tid = threadIdx.x, lane = tid & 63, wid = tid >> 6;
    const int lr = lane & 15, lg = lane >> 4;

    // stage Q block [64][64] fp32 -> hi/lo
#pragma unroll
    for (int it = 0; it < 4; ++it) {
        int idx = tid + it * 256;                   // 0..1023
        int r = idx >> 4, c4 = (idx & 15) * 4;
        float4 v = *(const float4*)&qkv[(size_t)(qb * 64 + r) * N_QKV + h * HDIM + c4];
        bfpair px = split_bf(v.x), py = split_bf(v.y);
        bfpair pz = split_bf(v.z), pw = split_bf(v.w);
        s16x4 hh, ll;
        hh.x = px.hi; hh.y = py.hi; hh.z = pz.hi; hh.w = pw.hi;
        ll.x = px.lo; ll.y = py.lo; ll.z = pz.lo; ll.w = pw.lo;
        *(s16x4*)&Qh[r * LDT + c4] = hh;
        *(s16x4*)&Ql[r * LDT + c4] = ll;
    }
    __syncthreads();

    s16x8 aqh[2], aql[2];
#pragma unroll
    for (int kc = 0; kc < 2; ++kc) {
        aqh[kc] = *(const s16x8*)&Qh[(wid * 16 + lr) * LDT + kc * 32 + lg * 8];
        aql[kc] = *(const s16x8*)&Ql[(wid * 16 + lr) * LDT + kc * 32 + lg * 8];
    }

    float m_run[4], l_run[4];
    f32x4 acc_o[4];
#pragma unroll
    for (int v = 0; v < 4; ++v) { m_run[v] = -1e30f; l_run[v] = 0.f; }
#pragma unroll
    for (int n = 0; n < 4; ++n) acc_o[n] = (f32x4){0.f, 0.f, 0.f, 0.f};

    const int qrow = qb * 64 + wid * 16 + lg * 4;   // + v

    for (int kvb = 0; kvb < S_LEN / 64; ++kvb) {
#pragma unroll
        for (int it = 0; it < 4; ++it) {
            int idx = tid + it * 256;
            int r = idx >> 4, c4 = (idx & 15) * 4;
            float4 kv = *(const float4*)&qkv[(size_t)(kvb * 64 + r) * N_QKV + DMODEL + h * HDIM + c4];
            bfpair px = split_bf(kv.x), py = split_bf(kv.y);
            bfpair pz = split_bf(kv.z), pw = split_bf(kv.w);
            s16x4 hh, ll;
            hh.x = px.hi; hh.y = py.hi; hh.z = pz.hi; hh.w = pw.hi;
            ll.x = px.lo; ll.y = py.lo; ll.z = pz.lo; ll.w = pw.lo;
            *(s16x4*)&Kh[r * LDT + c4] = hh;
            *(s16x4*)&Kl[r * LDT + c4] = ll;
            float4 vv = *(const float4*)&qkv[(size_t)(kvb * 64 + r) * N_QKV + 2 * DMODEL + h * HDIM + c4];
            VTs[(c4 + 0) * LDT + r] = f2bf(vv.x);
            VTs[(c4 + 1) * LDT + r] = f2bf(vv.y);
            VTs[(c4 + 2) * LDT + r] = f2bf(vv.z);
            VTs[(c4 + 3) * LDT + r] = f2bf(vv.w);
        }
        __syncthreads();

        // S = Q @ K^T with split hi/lo (3 mfma per fragment pair)
        f32x4 sc[4];
#pragma unroll
        for (int n = 0; n < 4; ++n) sc[n] = (f32x4){0.f, 0.f, 0.f, 0.f};
#pragma unroll
        for (int kc = 0; kc < 2; ++kc)
#pragma unroll
            for (int n = 0; n < 4; ++n) {
                s16x8 bkh = *(const s16x8*)&Kh[(n * 16 + lr) * LDT + kc * 32 + lg * 8];
                s16x8 bkl = *(const s16x8*)&Kl[(n * 16 + lr) * LDT + kc * 32 + lg * 8];
                sc[n] = __builtin_amdgcn_mfma_f32_16x16x32_bf16(aqh[kc], bkh, sc[n], 0, 0, 0);
                sc[n] = __builtin_amdgcn_mfma_f32_16x16x32_bf16(aqh[kc], bkl, sc[n], 0, 0, 0);
                sc[n] = __builtin_amdgcn_mfma_f32_16x16x32_bf16(aql[kc], bkh, sc[n], 0, 0, 0);
            }

        // causal mask + soft-threshold; row stats
        float p[4][4], tmax[4];
#pragma unroll
        for (int v = 0; v < 4; ++v) tmax[v] = -1e30f;
#pragma unroll
        for (int n = 0; n < 4; ++n) {
            int key = kvb * 64 + n * 16 + lr;
#pragma unroll
            for (int v = 0; v < 4; ++v) {
                float w;
                if (key > qrow + v) {
                    w = CMASK;
                } else {
                    float sv = sc[n][v];
                    float sig = 1.f / (1.f + __expf(-SLOPE * sv));
                    w = CMASK + (sv - CMASK) * sig;
                }
                p[n][v] = w;
                tmax[v] = fmaxf(tmax[v], w);
            }
        }
#pragma unroll
        for (int v = 0; v < 4; ++v)
#pragma unroll
            for (int msk = 1; msk < 16; msk <<= 1)
                tmax[v] = fmaxf(tmax[v], __shfl_xor(tmax[v], msk, 64));

        float scale[4], rsum[4];
#pragma unroll
        for (int v = 0; v < 4; ++v) {
            float mn = fmaxf(m_run[v], tmax[v]);
            scale[v] = __expf(m_run[v] - mn);
            m_run[v] = mn;
            rsum[v] = 0.f;
        }
#pragma unroll
        for (int n = 0; n < 4; ++n)
#pragma unroll
            for (int v = 0; v < 4; ++v) {
                float e = __expf(p[n][v] - m_run[v]);
                p[n][v] = e;
                rsum[v] += e;
            }
#pragma unroll
        for (int v = 0; v < 4; ++v) {
#pragma unroll
            for (int msk = 1; msk < 16; msk <<= 1)
                rsum[v] += __shfl_xor(rsum[v], msk, 64);
            l_run[v] = l_run[v] * scale[v] + rsum[v];
        }
#pragma unroll
        for (int n = 0; n < 4; ++n)
#pragma unroll
            for (int v = 0; v < 4; ++v) acc_o[n][v] *= scale[v];

        // P (D-layout) -> LDS -> A-frag layout (wave-local)
#pragma unroll
        for (int n = 0; n < 4; ++n)
#pragma unroll
            for (int v = 0; v < 4; ++v)
                Ps[wid][(lg * 4 + v) * LDT + 16 * n + lr] = f2bf(p[n][v]);
        asm volatile("s_waitcnt lgkmcnt(0)" ::: "memory");

        s16x8 pa0 = *(const s16x8*)&Ps[wid][lr * LDT + lg * 8];
        s16x8 pa1 = *(const s16x8*)&Ps[wid][lr * LDT + 32 + lg * 8];
#pragma unroll
        for (int n = 0; n < 4; ++n) {
            s16x8 bv0 = *(const s16x8*)&VTs[(16 * n + lr) * LDT + lg * 8];
            s16x8 bv1 = *(const s16x8*)&VTs[(16 * n + lr) * LDT + 32 + lg * 8];
            acc_o[n] = __builtin_amdgcn_mfma_f32_16x16x32_bf16(pa0, bv0, acc_o[n], 0, 0, 0);
            acc_o[n] = __builtin_amdgcn_mfma_f32_16x16x32_bf16(pa1, bv1, acc_o[n], 0, 0, 0);
        }

        // block-uniform early exit: past the diagonal, once every row's
        // exp(CMASK - m) underflows to f32 0, remaining (fully-masked)
        // blocks contribute exactly nothing -- matching numpy exp underflow.
        int ok = (kvb >= qb);
#pragma unroll
        for (int v = 0; v < 4; ++v)
            ok = ok && (m_run[v] > CMASK + 100.f);
        if (__syncthreads_and(ok)) break;   // doubles as the inter-iter barrier
    }

    // normalize + store fp32
#pragma unroll
    for (int n = 0; n < 4; ++n)
#pragma unroll
        for (int v = 0; v < 4; ++v) {
            int row = qrow + v;
            int col = h * HDIM + 16 * n + lr;
            attn_out[(size_t)row * DMODEL + col] = acc_o[n][v] / l_run[v];
        }
}

extern "C" void kernel_launch(void* const* d_in, const int* in_sizes, int n_in,
                              void* d_out, int out_size, void* d_ws, size_t ws_size,
                              hipStream_t stream)
{
    (void)in_sizes; (void)n_in; (void)out_size; (void)ws_size;
    const float* hs   = (const float*)d_in[0];
    const float* wqkv = (const float*)d_in[1];
    const float* bqkv = (const float*)d_in[2];
    const float* wprj = (const float*)d_in[3];
    const float* bprj = (const float*)d_in[4];

    float* qkv  = (float*)d_ws;                                          // [2048][3072] f32, 24 MiB
    float* attn = (float*)((char*)d_ws + (size_t)S_LEN * N_QKV * 4);     // [2048][1024] f32, 8 MiB

    gemm_split<N_QKV, true><<<dim3(N_QKV / 128, S_LEN / 128), 256, 0, stream>>>(
        hs, wqkv, bqkv, qkv, DMODEL);
    attn_fwd<<<dim3(S_LEN / 64, NHEAD), 256, 0, stream>>>(qkv, attn);
    gemm_split<DMODEL, false><<<dim3(DMODEL / 128, S_LEN / 128), 256, 0, stream>>>(
        attn, wprj, bprj, (float*)d_out, DMODEL);
}

// Round 5
// 204.075 us; speedup vs baseline: 2.0614x; 2.0614x over previous
//
#include <hip/hip_runtime.h>

// GPT2 attention w/ soft-threshold pruning — round 5.
// All matmuls: bf16 MFMA 16x16x32, split-bf16 (hi+lo) on score-critical paths.
// Dataflow: prep (split hs; transpose+split Wqkv) -> GEMM1 -> (transpose Wproj,
// transpose V) -> flash-attn -> GEMM2. All hot staging uses global_load_lds
// (16B) into XOR-swizzled linear LDS (swizzle applied on the per-lane global
// source address, rule: both-sides-or-neither).

#define S_LEN 2048
#define DM    1024
#define NH    16
#define HD    64
#define NQKV  3072
#define SLOPE 10.0f
#define CMASK -10000.0f

typedef short s16x4 __attribute__((ext_vector_type(4)));
typedef short s16x8 __attribute__((ext_vector_type(8)));
typedef float f32x4 __attribute__((ext_vector_type(4)));

#define MFMA16(a,b,c) __builtin_amdgcn_mfma_f32_16x16x32_bf16(a,b,c,0,0,0)
#define GLDS16(g,l) __builtin_amdgcn_global_load_lds( \
    (const __attribute__((address_space(1))) void*)(g), \
    (__attribute__((address_space(3))) void*)(l), 16, 0, 0)

__device__ __forceinline__ short f2bf(float f){
    unsigned u = __float_as_uint(f);
    u += 0x7fffu + ((u >> 16) & 1u);          // RNE
    return (short)(u >> 16);
}
struct bfpair { short hi, lo; };
__device__ __forceinline__ bfpair split_bf(float x){
    bfpair r; r.hi = f2bf(x);
    float fh = __uint_as_float(((unsigned)(unsigned short)r.hi) << 16);
    r.lo = f2bf(x - fh);
    return r;
}

// Stage a [ROWS][64] bf16 tile via global_load_lds. Storage swizzle: 16B group
// g of row r holds global k-group (g ^ (r&7)). gbase includes row0/col0 offset.
template<int ROWS>
__device__ __forceinline__ void stage_tile(const short* gbase, int rstride,
                                           short* lds, int tid){
    const int lane = tid & 63, wid = tid >> 6;
#pragma unroll
    for (int it = 0; it < ROWS/32; ++it){
        int s = it*256 + wid*64 + lane;
        int row = s >> 3, grp = s & 7;
        const short* src = gbase + (size_t)row*rstride + ((grp ^ (row & 7)) << 3);
        GLDS16(src, lds + (size_t)(it*256 + wid*64)*8);
    }
}
// Swizzled fragment read: 16B at (row, k-group kg).
__device__ __forceinline__ s16x8 frag(const short* lds, int row, int kg){
    return *(const s16x8*)&lds[row*64 + ((kg ^ (row & 7)) << 3)];
}

// ---------------- GEMM 128x128, BK=64, 4 waves (2x2 of 64x64) ----------------
// A = Ah/Al bf16 [M][1024] rows; B = Bh(/Bl) bf16 [N][1024] rows (pre-transposed).
// QKV epilogue: split q,k -> (hi,lo), v -> bf16, into [s][h*64+d] arrays.
template<bool WSPLIT, bool QKV>
__global__ __launch_bounds__(256)
void gemm_kern(const short* __restrict__ Ahg, const short* __restrict__ Alg,
               const short* __restrict__ Bhg, const short* __restrict__ Blg,
               const float* __restrict__ bias,
               short* __restrict__ o0h, short* __restrict__ o0l,
               short* __restrict__ o1h, short* __restrict__ o1l,
               short* __restrict__ o2,  float* __restrict__ oproj)
{
    __shared__ __align__(16) short Ah_s[128*64];
    __shared__ __align__(16) short Al_s[128*64];
    __shared__ __align__(16) short Bh_s[128*64];
    __shared__ __align__(16) short Bl_s[WSPLIT ? 128*64 : 8];

    const int tid = threadIdx.x, lane = tid & 63, wid = tid >> 6;
    const int lr = lane & 15, lg = lane >> 4;
    const int brow = blockIdx.y*128, bcol = blockIdx.x*128;
    const int wm = (wid >> 1)*64, wn = (wid & 1)*64;

    f32x4 acc[4][4];
#pragma unroll
    for (int m = 0; m < 4; ++m)
#pragma unroll
        for (int n = 0; n < 4; ++n) acc[m][n] = (f32x4){0.f,0.f,0.f,0.f};

    for (int k0 = 0; k0 < DM; k0 += 64){
        stage_tile<128>(Ahg + (size_t)brow*DM + k0, DM, Ah_s, tid);
        stage_tile<128>(Alg + (size_t)brow*DM + k0, DM, Al_s, tid);
        stage_tile<128>(Bhg + (size_t)bcol*DM + k0, DM, Bh_s, tid);
        if constexpr (WSPLIT)
            stage_tile<128>(Blg + (size_t)bcol*DM + k0, DM, Bl_s, tid);
        __syncthreads();
#pragma unroll
        for (int kc = 0; kc < 2; ++kc){
            s16x8 ah[4], al[4], bh[4], bl[4];
#pragma unroll
            for (int m = 0; m < 4; ++m){
                ah[m] = frag(Ah_s, wm + m*16 + lr, kc*4 + lg);
                al[m] = frag(Al_s, wm + m*16 + lr, kc*4 + lg);
            }
#pragma unroll
            for (int n = 0; n < 4; ++n){
                bh[n] = frag(Bh_s, wn + n*16 + lr, kc*4 + lg);
                if constexpr (WSPLIT)
                    bl[n] = frag(Bl_s, wn + n*16 + lr, kc*4 + lg);
            }
#pragma unroll
            for (int m = 0; m < 4; ++m)
#pragma unroll
                for (int n = 0; n < 4; ++n){
                    acc[m][n] = MFMA16(ah[m], bh[n], acc[m][n]);
                    if constexpr (WSPLIT)
                        acc[m][n] = MFMA16(ah[m], bl[n], acc[m][n]);
                    acc[m][n] = MFMA16(al[m], bh[n], acc[m][n]);
                }
        }
        __syncthreads();
    }

    // epilogue: D layout col=lane&15, row=(lane>>4)*4+v
    const int sec = bcol >> 10;     // block-uniform: 0=q 1=k 2=v (QKV only)
#pragma unroll
    for (int m = 0; m < 4; ++m)
#pragma unroll
        for (int n = 0; n < 4; ++n){
            int row  = brow + wm + m*16 + lg*4;
            int gcol = bcol + wn + n*16 + lr;
            float bv = bias[gcol];
#pragma unroll
            for (int v = 0; v < 4; ++v){
                float val = acc[m][n][v] + bv;
                if constexpr (QKV){
                    int col1 = gcol & 1023;
                    size_t o = (size_t)(row + v)*DM + col1;
                    if (sec == 0){ bfpair p = split_bf(val); o0h[o] = p.hi; o0l[o] = p.lo; }
                    else if (sec == 1){ bfpair p = split_bf(val); o1h[o] = p.hi; o1l[o] = p.lo; }
                    else { o2[o] = f2bf(val); }
                } else {
                    oproj[(size_t)(row + v)*DM + gcol] = val;
                }
            }
        }
}

// ---------------- prep: split fp32 -> (hi, lo) bf16, elementwise ----------------
__global__ __launch_bounds__(256)
void split_f32(const float* __restrict__ x, short* __restrict__ h,
               short* __restrict__ l, int n4)
{
    int i = blockIdx.x*256 + threadIdx.x;
    if (i >= n4) return;
    float4 v = *(const float4*)&x[(size_t)i*4];
    bfpair a = split_bf(v.x), b = split_bf(v.y), c = split_bf(v.z), d = split_bf(v.w);
    s16x4 hv, lv;
    hv.x = a.hi; hv.y = b.hi; hv.z = c.hi; hv.w = d.hi;
    lv.x = a.lo; lv.y = b.lo; lv.z = c.lo; lv.w = d.lo;
    *(s16x4*)&h[(size_t)i*4] = hv;
    *(s16x4*)&l[(size_t)i*4] = lv;
}

// ---------------- prep: W [1024][N] f32 -> W^T [N][1024] bf16 (hi[,lo]) -------
template<bool SPL>
__global__ __launch_bounds__(256)
void wtrans(const float* __restrict__ W, int N, short* __restrict__ Th,
            short* __restrict__ Tl)
{
    __shared__ float t[64][65];
    const int tid = threadIdx.x;
    const int tn = blockIdx.x*64, tk = blockIdx.y*64;
#pragma unroll
    for (int it = 0; it < 4; ++it){
        int idx = tid + it*256;
        int r = idx >> 4, c4 = (idx & 15)*4;
        float4 v = *(const float4*)&W[(size_t)(tk + r)*N + tn + c4];
        t[r][c4] = v.x; t[r][c4+1] = v.y; t[r][c4+2] = v.z; t[r][c4+3] = v.w;
    }
    __syncthreads();
#pragma unroll
    for (int it = 0; it < 4; ++it){
        int idx = tid + it*256;
        int n = idx >> 4, c4 = (idx & 15)*4;
        s16x4 hv, lv;
#pragma unroll
        for (int j = 0; j < 4; ++j){
            bfpair p = split_bf(t[c4+j][n]);
            hv[j] = p.hi; lv[j] = p.lo;
        }
        *(s16x4*)&Th[(size_t)(tn + n)*DM + tk + c4] = hv;
        if constexpr (SPL) *(s16x4*)&Tl[(size_t)(tn + n)*DM + tk + c4] = lv;
    }
}

// ---------------- prep: V [2048][1024] bf16 -> Vt [1024][2048] bf16 -----------
__global__ __launch_bounds__(256)
void vtrans(const short* __restrict__ Vb, short* __restrict__ Vt)
{
    __shared__ short t[64][66];
    const int tid = threadIdx.x;
    const int td = blockIdx.x*64, ts = blockIdx.y*64;
#pragma unroll
    for (int it = 0; it < 4; ++it){
        int idx = tid + it*256;
        int r = idx >> 4, c4 = (idx & 15)*4;
        s16x4 v = *(const s16x4*)&Vb[(size_t)(ts + r)*DM + td + c4];
        t[r][c4] = v.x; t[r][c4+1] = v.y; t[r][c4+2] = v.z; t[r][c4+3] = v.w;
    }
    __syncthreads();
#pragma unroll
    for (int it = 0; it < 4; ++it){
        int idx = tid + it*256;
        int n = idx >> 4, c4 = (idx & 15)*4;
        s16x4 o;
#pragma unroll
        for (int j = 0; j < 4; ++j) o[j] = t[c4+j][n];
        *(s16x4*)&Vt[(size_t)(td + n)*S_LEN + ts + c4] = o;
    }
}

// ---------------- Flash attention with soft-threshold pruning ----------------
// grid (32 qb, 16 h), 4 waves; wave w owns q rows [qb*64+w*16, +16).
// Full-row softmax semantics: masked-future entries at exactly CMASK take part;
// block-uniform break once exp(CMASK - m) underflows to 0 for every row.
__global__ __launch_bounds__(256)
void attn_fwd(const short* __restrict__ Qh, const short* __restrict__ Ql,
              const short* __restrict__ Kh, const short* __restrict__ Kl,
              const short* __restrict__ Vt,
              short* __restrict__ Oh, short* __restrict__ Ol)
{
    __shared__ __align__(16) short qh_s[64*64], ql_s[64*64];
    __shared__ __align__(16) short kh_s[64*64], kl_s[64*64];
    __shared__ __align__(16) short vt_s[64*64];       // [d][s-key], swizzled
    __shared__ __align__(16) short Ps[4][16*72];      // per-wave P re-layout

    const int qb = blockIdx.x, h = blockIdx.y;
    const int tid = threadIdx.x, lane = tid & 63, wid = tid >> 6;
    const int lr = lane & 15, lg = lane >> 4;

    stage_tile<64>(Qh + (size_t)(qb*64)*DM + h*HD, DM, qh_s, tid);
    stage_tile<64>(Ql + (size_t)(qb*64)*DM + h*HD, DM, ql_s, tid);
    __syncthreads();

    s16x8 aqh[2], aql[2];
#pragma unroll
    for (int kc = 0; kc < 2; ++kc){
        aqh[kc] = frag(qh_s, wid*16 + lr, kc*4 + lg);
        aql[kc] = frag(ql_s, wid*16 + lr, kc*4 + lg);
    }
    __syncthreads();   // frags in regs before K staging reuses nothing; keep order clean

    float m_run[4], l_run[4];
    f32x4 acc_o[4];
#pragma unroll
    for (int v = 0; v < 4; ++v){ m_run[v] = -1e30f; l_run[v] = 0.f; }
#pragma unroll
    for (int n = 0; n < 4; ++n) acc_o[n] = (f32x4){0.f,0.f,0.f,0.f};

    const int qrow = qb*64 + wid*16 + lg*4;

    for (int kvb = 0; kvb < S_LEN/64; ++kvb){
        stage_tile<64>(Kh + (size_t)(kvb*64)*DM + h*HD, DM, kh_s, tid);
        stage_tile<64>(Kl + (size_t)(kvb*64)*DM + h*HD, DM, kl_s, tid);
        stage_tile<64>(Vt + (size_t)(h*HD)*S_LEN + kvb*64, S_LEN, vt_s, tid);
        __syncthreads();

        // S = Q K^T, split hi/lo (3 mfma per fragment pair)
        f32x4 sc[4];
#pragma unroll
        for (int n = 0; n < 4; ++n) sc[n] = (f32x4){0.f,0.f,0.f,0.f};
#pragma unroll
        for (int kc = 0; kc < 2; ++kc)
#pragma unroll
            for (int n = 0; n < 4; ++n){
                s16x8 bkh = frag(kh_s, n*16 + lr, kc*4 + lg);
                s16x8 bkl = frag(kl_s, n*16 + lr, kc*4 + lg);
                sc[n] = MFMA16(aqh[kc], bkh, sc[n]);
                sc[n] = MFMA16(aqh[kc], bkl, sc[n]);
                sc[n] = MFMA16(aql[kc], bkh, sc[n]);
            }

        // causal mask + soft-threshold; row stats
        float p[4][4], tmax[4];
#pragma unroll
        for (int v = 0; v < 4; ++v) tmax[v] = -1e30f;
#pragma unroll
        for (int n = 0; n < 4; ++n){
            int key = kvb*64 + n*16 + lr;
#pragma unroll
            for (int v = 0; v < 4; ++v){
                float w;
                if (key > qrow + v) w = CMASK;
                else {
                    float sv = sc[n][v];
                    float sig = 1.f / (1.f + __expf(-SLOPE*sv));
                    w = CMASK + (sv - CMASK)*sig;
                }
                p[n][v] = w;
                tmax[v] = fmaxf(tmax[v], w);
            }
        }
#pragma unroll
        for (int v = 0; v < 4; ++v)
#pragma unroll
            for (int msk = 1; msk < 16; msk <<= 1)
                tmax[v] = fmaxf(tmax[v], __shfl_xor(tmax[v], msk, 64));

        float scale[4], rsum[4];
#pragma unroll
        for (int v = 0; v < 4; ++v){
            float mn = fmaxf(m_run[v], tmax[v]);
            scale[v] = __expf(m_run[v] - mn);
            m_run[v] = mn;
            rsum[v] = 0.f;
        }
#pragma unroll
        for (int n = 0; n < 4; ++n)
#pragma unroll
            for (int v = 0; v < 4; ++v){
                float e = __expf(p[n][v] - m_run[v]);
                p[n][v] = e;
                rsum[v] += e;
            }
#pragma unroll
        for (int v = 0; v < 4; ++v){
#pragma unroll
            for (int msk = 1; msk < 16; msk <<= 1)
                rsum[v] += __shfl_xor(rsum[v], msk, 64);
            l_run[v] = l_run[v]*scale[v] + rsum[v];
        }
#pragma unroll
        for (int n = 0; n < 4; ++n)
#pragma unroll
            for (int v = 0; v < 4; ++v) acc_o[n][v] *= scale[v];

        // P (D-layout) -> per-wave LDS -> A-frag layout
#pragma unroll
        for (int n = 0; n < 4; ++n)
#pragma unroll
            for (int v = 0; v < 4; ++v)
                Ps[wid][(lg*4 + v)*72 + 16*n + lr] = f2bf(p[n][v]);
        asm volatile("s_waitcnt lgkmcnt(0)" ::: "memory");

        s16x8 pa0 = *(const s16x8*)&Ps[wid][lr*72 + lg*8];
        s16x8 pa1 = *(const s16x8*)&Ps[wid][lr*72 + 32 + lg*8];
#pragma unroll
        for (int n = 0; n < 4; ++n){
            s16x8 bv0 = frag(vt_s, 16*n + lr, lg);       // keys 0..31
            s16x8 bv1 = frag(vt_s, 16*n + lr, 4 + lg);   // keys 32..63
            acc_o[n] = MFMA16(pa0, bv0, acc_o[n]);
            acc_o[n] = MFMA16(pa1, bv1, acc_o[n]);
        }

        // block-uniform early exit (also the loop barrier)
        int ok = (kvb >= qb);
#pragma unroll
        for (int v = 0; v < 4; ++v)
            ok = ok && (m_run[v] > CMASK + 100.f);
        if (__syncthreads_and(ok)) break;
    }

    // normalize + split-store bf16 hi/lo
#pragma unroll
    for (int n = 0; n < 4; ++n)
#pragma unroll
        for (int v = 0; v < 4; ++v){
            int row = qrow + v;
            int col = h*HD + 16*n + lr;
            bfpair p = split_bf(acc_o[n][v] / l_run[v]);
            Oh[(size_t)row*DM + col] = p.hi;
            Ol[(size_t)row*DM + col] = p.lo;
        }
}

extern "C" void kernel_launch(void* const* d_in, const int* in_sizes, int n_in,
                              void* d_out, int out_size, void* d_ws, size_t ws_size,
                              hipStream_t stream)
{
    (void)in_sizes; (void)n_in; (void)out_size; (void)ws_size;
    const float* hs   = (const float*)d_in[0];
    const float* wqkv = (const float*)d_in[1];
    const float* bqkv = (const float*)d_in[2];
    const float* wprj = (const float*)d_in[3];
    const float* bprj = (const float*)d_in[4];

    char* p = (char*)d_ws;                       // 44 MiB used
    short* Ahg  = (short*)(p + (0ull  << 20));   // 4 MiB  (later: Oh)
    short* Alg  = (short*)(p + (4ull  << 20));   // 4 MiB  (later: Ol)
    short* WqTh = (short*)(p + (8ull  << 20));   // 6 MiB  (later: WprojT)
    short* WqTl = (short*)(p + (14ull << 20));   // 6 MiB
    short* Qhg  = (short*)(p + (20ull << 20));   // 4 MiB
    short* Qlg  = (short*)(p + (24ull << 20));
    short* Khg  = (short*)(p + (28ull << 20));
    short* Klg  = (short*)(p + (32ull << 20));
    short* Vbg  = (short*)(p + (36ull << 20));
    short* Vtg  = (short*)(p + (40ull << 20));
    short* Oh = Ahg, * Ol = Alg;                 // reuse after GEMM1
    short* WpT = WqTh;                           // reuse after GEMM1

    split_f32<<<S_LEN*DM/4/256, 256, 0, stream>>>(hs, Ahg, Alg, S_LEN*DM/4);
    wtrans<true><<<dim3(NQKV/64, DM/64), 256, 0, stream>>>(wqkv, NQKV, WqTh, WqTl);

    gemm_kern<true, true><<<dim3(NQKV/128, S_LEN/128), 256, 0, stream>>>(
        Ahg, Alg, WqTh, WqTl, bqkv, Qhg, Qlg, Khg, Klg, Vbg, nullptr);

    wtrans<false><<<dim3(DM/64, DM/64), 256, 0, stream>>>(wprj, DM, WpT, nullptr);
    vtrans<<<dim3(DM/64, S_LEN/64), 256, 0, stream>>>(Vbg, Vtg);

    attn_fwd<<<dim3(S_LEN/64, NH), 256, 0, stream>>>(Qhg, Qlg, Khg, Klg, Vtg, Oh, Ol);

    gemm_kern<false, false><<<dim3(DM/128, S_LEN/128), 256, 0, stream>>>(
        Oh, Ol, WpT, nullptr, bprj, nullptr, nullptr, nullptr, nullptr, nullptr,
        (float*)d_out);
}

// Round 6
// 195.171 us; speedup vs baseline: 2.1555x; 1.0456x over previous
//
#include <hip/hip_runtime.h>

// GPT2 attention w/ soft-threshold pruning — round 6.
// Change vs r5: attention occupancy. 32-row q-tiles, 2-wave (128-thread)
// blocks, 1024-block grid (fully co-resident), complementary heavy/light
// tile placement, block-uniform mask-branch split. Math identical to r5.

#define S_LEN 2048
#define DM    1024
#define NH    16
#define HD    64
#define NQKV  3072
#define SLOPE 10.0f
#define CMASK -10000.0f
#define QROWS 32

typedef short s16x4 __attribute__((ext_vector_type(4)));
typedef short s16x8 __attribute__((ext_vector_type(8)));
typedef float f32x4 __attribute__((ext_vector_type(4)));

#define MFMA16(a,b,c) __builtin_amdgcn_mfma_f32_16x16x32_bf16(a,b,c,0,0,0)
#define GLDS16(g,l) __builtin_amdgcn_global_load_lds( \
    (const __attribute__((address_space(1))) void*)(g), \
    (__attribute__((address_space(3))) void*)(l), 16, 0, 0)

__device__ __forceinline__ short f2bf(float f){
    unsigned u = __float_as_uint(f);
    u += 0x7fffu + ((u >> 16) & 1u);          // RNE
    return (short)(u >> 16);
}
struct bfpair { short hi, lo; };
__device__ __forceinline__ bfpair split_bf(float x){
    bfpair r; r.hi = f2bf(x);
    float fh = __uint_as_float(((unsigned)(unsigned short)r.hi) << 16);
    r.lo = f2bf(x - fh);
    return r;
}

// Stage a [ROWS][64] bf16 tile via global_load_lds (16B/lane). Storage
// swizzle: 16B group g of row r holds global k-group (g ^ (r&7)).
template<int ROWS, int THREADS>
__device__ __forceinline__ void stage_tile(const short* gbase, int rstride,
                                           short* lds, int tid){
#pragma unroll
    for (int it = 0; it < ROWS*8/THREADS; ++it){
        int s = it*THREADS + tid;
        int row = s >> 3, grp = s & 7;
        const short* src = gbase + (size_t)row*rstride + ((grp ^ (row & 7)) << 3);
        GLDS16(src, lds + (size_t)s*8);
    }
}
// Swizzled fragment read: 16B at (row, k-group kg).
__device__ __forceinline__ s16x8 frag(const short* lds, int row, int kg){
    return *(const s16x8*)&lds[row*64 + ((kg ^ (row & 7)) << 3)];
}

// ---------------- GEMM 128x128, BK=64, 4 waves (2x2 of 64x64) ----------------
template<bool WSPLIT, bool QKV>
__global__ __launch_bounds__(256)
void gemm_kern(const short* __restrict__ Ahg, const short* __restrict__ Alg,
               const short* __restrict__ Bhg, const short* __restrict__ Blg,
               const float* __restrict__ bias,
               short* __restrict__ o0h, short* __restrict__ o0l,
               short* __restrict__ o1h, short* __restrict__ o1l,
               short* __restrict__ o2,  float* __restrict__ oproj)
{
    __shared__ __align__(16) short Ah_s[128*64];
    __shared__ __align__(16) short Al_s[128*64];
    __shared__ __align__(16) short Bh_s[128*64];
    __shared__ __align__(16) short Bl_s[WSPLIT ? 128*64 : 8];

    const int tid = threadIdx.x, lane = tid & 63, wid = tid >> 6;
    const int lr = lane & 15, lg = lane >> 4;
    const int brow = blockIdx.y*128, bcol = blockIdx.x*128;
    const int wm = (wid >> 1)*64, wn = (wid & 1)*64;

    f32x4 acc[4][4];
#pragma unroll
    for (int m = 0; m < 4; ++m)
#pragma unroll
        for (int n = 0; n < 4; ++n) acc[m][n] = (f32x4){0.f,0.f,0.f,0.f};

    for (int k0 = 0; k0 < DM; k0 += 64){
        stage_tile<128,256>(Ahg + (size_t)brow*DM + k0, DM, Ah_s, tid);
        stage_tile<128,256>(Alg + (size_t)brow*DM + k0, DM, Al_s, tid);
        stage_tile<128,256>(Bhg + (size_t)bcol*DM + k0, DM, Bh_s, tid);
        if constexpr (WSPLIT)
            stage_tile<128,256>(Blg + (size_t)bcol*DM + k0, DM, Bl_s, tid);
        __syncthreads();
#pragma unroll
        for (int kc = 0; kc < 2; ++kc){
            s16x8 ah[4], al[4], bh[4], bl[4];
#pragma unroll
            for (int m = 0; m < 4; ++m){
                ah[m] = frag(Ah_s, wm + m*16 + lr, kc*4 + lg);
                al[m] = frag(Al_s, wm + m*16 + lr, kc*4 + lg);
            }
#pragma unroll
            for (int n = 0; n < 4; ++n){
                bh[n] = frag(Bh_s, wn + n*16 + lr, kc*4 + lg);
                if constexpr (WSPLIT)
                    bl[n] = frag(Bl_s, wn + n*16 + lr, kc*4 + lg);
            }
#pragma unroll
            for (int m = 0; m < 4; ++m)
#pragma unroll
                for (int n = 0; n < 4; ++n){
                    acc[m][n] = MFMA16(ah[m], bh[n], acc[m][n]);
                    if constexpr (WSPLIT)
                        acc[m][n] = MFMA16(ah[m], bl[n], acc[m][n]);
                    acc[m][n] = MFMA16(al[m], bh[n], acc[m][n]);
                }
        }
        __syncthreads();
    }

    const int sec = bcol >> 10;     // block-uniform: 0=q 1=k 2=v (QKV only)
#pragma unroll
    for (int m = 0; m < 4; ++m)
#pragma unroll
        for (int n = 0; n < 4; ++n){
            int row  = brow + wm + m*16 + lg*4;
            int gcol = bcol + wn + n*16 + lr;
            float bv = bias[gcol];
#pragma unroll
            for (int v = 0; v < 4; ++v){
                float val = acc[m][n][v] + bv;
                if constexpr (QKV){
                    int col1 = gcol & 1023;
                    size_t o = (size_t)(row + v)*DM + col1;
                    if (sec == 0){ bfpair p = split_bf(val); o0h[o] = p.hi; o0l[o] = p.lo; }
                    else if (sec == 1){ bfpair p = split_bf(val); o1h[o] = p.hi; o1l[o] = p.lo; }
                    else { o2[o] = f2bf(val); }
                } else {
                    oproj[(size_t)(row + v)*DM + gcol] = val;
                }
            }
        }
}

// ---------------- prep kernels ----------------
__global__ __launch_bounds__(256)
void split_f32(const float* __restrict__ x, short* __restrict__ h,
               short* __restrict__ l, int n4)
{
    int i = blockIdx.x*256 + threadIdx.x;
    if (i >= n4) return;
    float4 v = *(const float4*)&x[(size_t)i*4];
    bfpair a = split_bf(v.x), b = split_bf(v.y), c = split_bf(v.z), d = split_bf(v.w);
    s16x4 hv, lv;
    hv.x = a.hi; hv.y = b.hi; hv.z = c.hi; hv.w = d.hi;
    lv.x = a.lo; lv.y = b.lo; lv.z = c.lo; lv.w = d.lo;
    *(s16x4*)&h[(size_t)i*4] = hv;
    *(s16x4*)&l[(size_t)i*4] = lv;
}

template<bool SPL>
__global__ __launch_bounds__(256)
void wtrans(const float* __restrict__ W, int N, short* __restrict__ Th,
            short* __restrict__ Tl)
{
    __shared__ float t[64][65];
    const int tid = threadIdx.x;
    const int tn = blockIdx.x*64, tk = blockIdx.y*64;
#pragma unroll
    for (int it = 0; it < 4; ++it){
        int idx = tid + it*256;
        int r = idx >> 4, c4 = (idx & 15)*4;
        float4 v = *(const float4*)&W[(size_t)(tk + r)*N + tn + c4];
        t[r][c4] = v.x; t[r][c4+1] = v.y; t[r][c4+2] = v.z; t[r][c4+3] = v.w;
    }
    __syncthreads();
#pragma unroll
    for (int it = 0; it < 4; ++it){
        int idx = tid + it*256;
        int n = idx >> 4, c4 = (idx & 15)*4;
        s16x4 hv, lv;
#pragma unroll
        for (int j = 0; j < 4; ++j){
            bfpair p = split_bf(t[c4+j][n]);
            hv[j] = p.hi; lv[j] = p.lo;
        }
        *(s16x4*)&Th[(size_t)(tn + n)*DM + tk + c4] = hv;
        if constexpr (SPL) *(s16x4*)&Tl[(size_t)(tn + n)*DM + tk + c4] = lv;
    }
}

__global__ __launch_bounds__(256)
void vtrans(const short* __restrict__ Vb, short* __restrict__ Vt)
{
    __shared__ short t[64][66];
    const int tid = threadIdx.x;
    const int td = blockIdx.x*64, ts = blockIdx.y*64;
#pragma unroll
    for (int it = 0; it < 4; ++it){
        int idx = tid + it*256;
        int r = idx >> 4, c4 = (idx & 15)*4;
        s16x4 v = *(const s16x4*)&Vb[(size_t)(ts + r)*DM + td + c4];
        t[r][c4] = v.x; t[r][c4+1] = v.y; t[r][c4+2] = v.z; t[r][c4+3] = v.w;
    }
    __syncthreads();
#pragma unroll
    for (int it = 0; it < 4; ++it){
        int idx = tid + it*256;
        int n = idx >> 4, c4 = (idx & 15)*4;
        s16x4 o;
#pragma unroll
        for (int j = 0; j < 4; ++j) o[j] = t[c4+j][n];
        *(s16x4*)&Vt[(size_t)(td + n)*S_LEN + ts + c4] = o;
    }
}

// ---------------- Flash attention with soft-threshold pruning ----------------
// 32-row q-tiles, 2 waves (128 thr); wave w owns rows [qt*32+w*16, +16).
// Full-row softmax semantics: masked-future entries at exactly CMASK take part;
// block-uniform break once exp(CMASK - m) underflows to 0 for every row.
__global__ __launch_bounds__(128)
void attn_fwd(const short* __restrict__ Qh, const short* __restrict__ Ql,
              const short* __restrict__ Kh, const short* __restrict__ Kl,
              const short* __restrict__ Vt,
              short* __restrict__ Oh, short* __restrict__ Ol)
{
    __shared__ __align__(16) short qh_s[QROWS*64], ql_s[QROWS*64];
    __shared__ __align__(16) short kh_s[64*64], kl_s[64*64];
    __shared__ __align__(16) short vt_s[64*64];       // [d][s-key], swizzled
    __shared__ __align__(16) short Ps[2][16*72];      // per-wave P re-layout

    const int bx = blockIdx.x, h = blockIdx.y;
    // complementary placement: ids 256 apart (likely same CU when the whole
    // grid is resident) get qt and 63-qt -> per-CU work ~constant.
    const int lid = bx + (h << 6);
    const int qt = ((lid >> 8) & 1) ? bx : (S_LEN/QROWS - 1) - bx;
    const int diag = (qt*QROWS + QROWS - 1) >> 6;     // last kv-block with live keys

    const int tid = threadIdx.x, lane = tid & 63, wid = tid >> 6;   // wid 0..1
    const int lr = lane & 15, lg = lane >> 4;

    stage_tile<QROWS,128>(Qh + (size_t)(qt*QROWS)*DM + h*HD, DM, qh_s, tid);
    stage_tile<QROWS,128>(Ql + (size_t)(qt*QROWS)*DM + h*HD, DM, ql_s, tid);
    __syncthreads();

    s16x8 aqh[2], aql[2];
#pragma unroll
    for (int kc = 0; kc < 2; ++kc){
        aqh[kc] = frag(qh_s, wid*16 + lr, kc*4 + lg);
        aql[kc] = frag(ql_s, wid*16 + lr, kc*4 + lg);
    }

    float m_run[4], l_run[4];
    f32x4 acc_o[4];
#pragma unroll
    for (int v = 0; v < 4; ++v){ m_run[v] = -1e30f; l_run[v] = 0.f; }
#pragma unroll
    for (int n = 0; n < 4; ++n) acc_o[n] = (f32x4){0.f,0.f,0.f,0.f};

    const int qrow = qt*QROWS + wid*16 + lg*4;

    for (int kvb = 0; kvb < S_LEN/64; ++kvb){
        stage_tile<64,128>(Kh + (size_t)(kvb*64)*DM + h*HD, DM, kh_s, tid);
        stage_tile<64,128>(Kl + (size_t)(kvb*64)*DM + h*HD, DM, kl_s, tid);
        stage_tile<64,128>(Vt + (size_t)(h*HD)*S_LEN + kvb*64, S_LEN, vt_s, tid);
        __syncthreads();

        // S = Q K^T, split hi/lo (3 mfma per fragment pair)
        f32x4 sc[4];
#pragma unroll
        for (int n = 0; n < 4; ++n) sc[n] = (f32x4){0.f,0.f,0.f,0.f};
#pragma unroll
        for (int kc = 0; kc < 2; ++kc)
#pragma unroll
            for (int n = 0; n < 4; ++n){
                s16x8 bkh = frag(kh_s, n*16 + lr, kc*4 + lg);
                s16x8 bkl = frag(kl_s, n*16 + lr, kc*4 + lg);
                sc[n] = MFMA16(aqh[kc], bkh, sc[n]);
                sc[n] = MFMA16(aqh[kc], bkl, sc[n]);
                sc[n] = MFMA16(aql[kc], bkh, sc[n]);
            }

        // soft-threshold (+ causal mask only on/past the diagonal block)
        float p[4][4], tmax[4];
#pragma unroll
        for (int v = 0; v < 4; ++v) tmax[v] = -1e30f;
        if (kvb >= diag){
#pragma unroll
            for (int n = 0; n < 4; ++n){
                int key = kvb*64 + n*16 + lr;
#pragma unroll
                for (int v = 0; v < 4; ++v){
                    float w;
                    if (key > qrow + v) w = CMASK;
                    else {
                        float sv = sc[n][v];
                        float sig = 1.f / (1.f + __expf(-SLOPE*sv));
                        w = CMASK + (sv - CMASK)*sig;
                    }
                    p[n][v] = w;
                    tmax[v] = fmaxf(tmax[v], w);
                }
            }
        } else {
#pragma unroll
            for (int n = 0; n < 4; ++n)
#pragma unroll
                for (int v = 0; v < 4; ++v){
                    float sv = sc[n][v];
                    float sig = 1.f / (1.f + __expf(-SLOPE*sv));
                    float w = CMASK + (sv - CMASK)*sig;
                    p[n][v] = w;
                    tmax[v] = fmaxf(tmax[v], w);
                }
        }
#pragma unroll
        for (int v = 0; v < 4; ++v)
#pragma unroll
            for (int msk = 1; msk < 16; msk <<= 1)
                tmax[v] = fmaxf(tmax[v], __shfl_xor(tmax[v], msk, 64));

        float scale[4], rsum[4];
#pragma unroll
        for (int v = 0; v < 4; ++v){
            float mn = fmaxf(m_run[v], tmax[v]);
            scale[v] = __expf(m_run[v] - mn);
            m_run[v] = mn;
            rsum[v] = 0.f;
        }
#pragma unroll
        for (int n = 0; n < 4; ++n)
#pragma unroll
            for (int v = 0; v < 4; ++v){
                float e = __expf(p[n][v] - m_run[v]);
                p[n][v] = e;
                rsum[v] += e;
            }
#pragma unroll
        for (int v = 0; v < 4; ++v){
#pragma unroll
            for (int msk = 1; msk < 16; msk <<= 1)
                rsum[v] += __shfl_xor(rsum[v], msk, 64);
            l_run[v] = l_run[v]*scale[v] + rsum[v];
        }
#pragma unroll
        for (int n = 0; n < 4; ++n)
#pragma unroll
            for (int v = 0; v < 4; ++v) acc_o[n][v] *= scale[v];

        // P (D-layout) -> per-wave LDS -> A-frag layout
#pragma unroll
        for (int n = 0; n < 4; ++n)
#pragma unroll
            for (int v = 0; v < 4; ++v)
                Ps[wid][(lg*4 + v)*72 + 16*n + lr] = f2bf(p[n][v]);
        asm volatile("s_waitcnt lgkmcnt(0)" ::: "memory");

        s16x8 pa0 = *(const s16x8*)&Ps[wid][lr*72 + lg*8];
        s16x8 pa1 = *(const s16x8*)&Ps[wid][lr*72 + 32 + lg*8];
#pragma unroll
        for (int n = 0; n < 4; ++n){
            s16x8 bv0 = frag(vt_s, 16*n + lr, lg);       // keys 0..31
            s16x8 bv1 = frag(vt_s, 16*n + lr, 4 + lg);   // keys 32..63
            acc_o[n] = MFMA16(pa0, bv0, acc_o[n]);
            acc_o[n] = MFMA16(pa1, bv1, acc_o[n]);
        }

        // block-uniform early exit (also the loop barrier)
        int ok = (kvb >= diag);
#pragma unroll
        for (int v = 0; v < 4; ++v)
            ok = ok && (m_run[v] > CMASK + 100.f);
        if (__syncthreads_and(ok)) break;
    }

    // normalize + split-store bf16 hi/lo
#pragma unroll
    for (int n = 0; n < 4; ++n)
#pragma unroll
        for (int v = 0; v < 4; ++v){
            int row = qrow + v;
            int col = h*HD + 16*n + lr;
            bfpair p = split_bf(acc_o[n][v] / l_run[v]);
            Oh[(size_t)row*DM + col] = p.hi;
            Ol[(size_t)row*DM + col] = p.lo;
        }
}

extern "C" void kernel_launch(void* const* d_in, const int* in_sizes, int n_in,
                              void* d_out, int out_size, void* d_ws, size_t ws_size,
                              hipStream_t stream)
{
    (void)in_sizes; (void)n_in; (void)out_size; (void)ws_size;
    const float* hs   = (const float*)d_in[0];
    const float* wqkv = (const float*)d_in[1];
    const float* bqkv = (const float*)d_in[2];
    const float* wprj = (const float*)d_in[3];
    const float* bprj = (const float*)d_in[4];

    char* p = (char*)d_ws;                       // 44 MiB used
    short* Ahg  = (short*)(p + (0ull  << 20));   // 4 MiB  (later: Oh)
    short* Alg  = (short*)(p + (4ull  << 20));   // 4 MiB  (later: Ol)
    short* WqTh = (short*)(p + (8ull  << 20));   // 6 MiB  (later: WprojT)
    short* WqTl = (short*)(p + (14ull << 20));   // 6 MiB
    short* Qhg  = (short*)(p + (20ull << 20));   // 4 MiB
    short* Qlg  = (short*)(p + (24ull << 20));
    short* Khg  = (short*)(p + (28ull << 20));
    short* Klg  = (short*)(p + (32ull << 20));
    short* Vbg  = (short*)(p + (36ull << 20));
    short* Vtg  = (short*)(p + (40ull << 20));
    short* Oh = Ahg, * Ol = Alg;                 // reuse after GEMM1
    short* WpT = WqTh;                           // reuse after GEMM1

    split_f32<<<S_LEN*DM/4/256, 256, 0, stream>>>(hs, Ahg, Alg, S_LEN*DM/4);
    wtrans<true><<<dim3(NQKV/64, DM/64), 256, 0, stream>>>(wqkv, NQKV, WqTh, WqTl);

    gemm_kern<true, true><<<dim3(NQKV/128, S_LEN/128), 256, 0, stream>>>(
        Ahg, Alg, WqTh, WqTl, bqkv, Qhg, Qlg, Khg, Klg, Vbg, nullptr);

    wtrans<false><<<dim3(DM/64, DM/64), 256, 0, stream>>>(wprj, DM, WpT, nullptr);
    vtrans<<<dim3(DM/64, S_LEN/64), 256, 0, stream>>>(Vbg, Vtg);

    attn_fwd<<<dim3(S_LEN/QROWS, NH), 128, 0, stream>>>(Qhg, Qlg, Khg, Klg, Vtg, Oh, Ol);

    gemm_kern<false, false><<<dim3(DM/128, S_LEN/128), 256, 0, stream>>>(
        Oh, Ol, WpT, nullptr, bprj, nullptr, nullptr, nullptr, nullptr, nullptr,
        (float*)d_out);
}

// Round 7
// 173.307 us; speedup vs baseline: 2.4274x; 1.1262x over previous
//
#include <hip/hip_runtime.h>

// GPT2 attention w/ soft-threshold pruning — round 7.
// attn redesign: 1-wave (64-thr) jobs of 16 q-rows; MFMA fragments read
// DIRECTLY from global (L2-resident, XCD-pinned heads) — no K/V/Q LDS staging
// (zero reuse at 16 rows/wave). Masked-future tail computed analytically via
// per-head V suffix sums (exp(C-m) uniform weight), so the kv loop is a static
// diag+1 trips and jobs are scheduled LPT (descending diag) with HW refill.
// K-lo split dropped in QK^T (Q stays split): est absmax <= 0.015.

#define S_LEN 2048
#define DM    1024
#define NH    16
#define HD    64
#define NQKV  3072
#define SLOPE 10.0f
#define CMASK -10000.0f

typedef short s16x4 __attribute__((ext_vector_type(4)));
typedef short s16x8 __attribute__((ext_vector_type(8)));
typedef float f32x4 __attribute__((ext_vector_type(4)));

#define MFMA16(a,b,c) __builtin_amdgcn_mfma_f32_16x16x32_bf16(a,b,c,0,0,0)
#define GLDS16(g,l) __builtin_amdgcn_global_load_lds( \
    (const __attribute__((address_space(1))) void*)(g), \
    (__attribute__((address_space(3))) void*)(l), 16, 0, 0)

__device__ __forceinline__ short f2bf(float f){
    unsigned u = __float_as_uint(f);
    u += 0x7fffu + ((u >> 16) & 1u);          // RNE
    return (short)(u >> 16);
}
__device__ __forceinline__ float bf2f(short x){
    return __uint_as_float(((unsigned)(unsigned short)x) << 16);
}
struct bfpair { short hi, lo; };
__device__ __forceinline__ bfpair split_bf(float x){
    bfpair r; r.hi = f2bf(x);
    r.lo = f2bf(x - bf2f(r.hi));
    return r;
}

// ---- GEMM staging: [ROWS][64] bf16 tile via global_load_lds, XOR-swizzled ----
template<int ROWS, int THREADS>
__device__ __forceinline__ void stage_tile(const short* gbase, int rstride,
                                           short* lds, int tid){
#pragma unroll
    for (int it = 0; it < ROWS*8/THREADS; ++it){
        int s = it*THREADS + tid;
        int row = s >> 3, grp = s & 7;
        const short* src = gbase + (size_t)row*rstride + ((grp ^ (row & 7)) << 3);
        GLDS16(src, lds + (size_t)s*8);
    }
}
__device__ __forceinline__ s16x8 frag(const short* lds, int row, int kg){
    return *(const s16x8*)&lds[row*64 + ((kg ^ (row & 7)) << 3)];
}

// ---------------- GEMM 128x128, BK=64, 4 waves (2x2 of 64x64) ----------------
template<bool WSPLIT, bool QKV>
__global__ __launch_bounds__(256)
void gemm_kern(const short* __restrict__ Ahg, const short* __restrict__ Alg,
               const short* __restrict__ Bhg, const short* __restrict__ Blg,
               const float* __restrict__ bias,
               short* __restrict__ o0h, short* __restrict__ o0l,
               short* __restrict__ o1h,
               short* __restrict__ o2,  float* __restrict__ oproj)
{
    __shared__ __align__(16) short Ah_s[128*64];
    __shared__ __align__(16) short Al_s[128*64];
    __shared__ __align__(16) short Bh_s[128*64];
    __shared__ __align__(16) short Bl_s[WSPLIT ? 128*64 : 8];

    const int tid = threadIdx.x, lane = tid & 63, wid = tid >> 6;
    const int lr = lane & 15, lg = lane >> 4;
    const int brow = blockIdx.y*128, bcol = blockIdx.x*128;
    const int wm = (wid >> 1)*64, wn = (wid & 1)*64;

    f32x4 acc[4][4];
#pragma unroll
    for (int m = 0; m < 4; ++m)
#pragma unroll
        for (int n = 0; n < 4; ++n) acc[m][n] = (f32x4){0.f,0.f,0.f,0.f};

    for (int k0 = 0; k0 < DM; k0 += 64){
        stage_tile<128,256>(Ahg + (size_t)brow*DM + k0, DM, Ah_s, tid);
        stage_tile<128,256>(Alg + (size_t)brow*DM + k0, DM, Al_s, tid);
        stage_tile<128,256>(Bhg + (size_t)bcol*DM + k0, DM, Bh_s, tid);
        if constexpr (WSPLIT)
            stage_tile<128,256>(Blg + (size_t)bcol*DM + k0, DM, Bl_s, tid);
        __syncthreads();
#pragma unroll
        for (int kc = 0; kc < 2; ++kc){
            s16x8 ah[4], al[4], bh[4], bl[4];
#pragma unroll
            for (int m = 0; m < 4; ++m){
                ah[m] = frag(Ah_s, wm + m*16 + lr, kc*4 + lg);
                al[m] = frag(Al_s, wm + m*16 + lr, kc*4 + lg);
            }
#pragma unroll
            for (int n = 0; n < 4; ++n){
                bh[n] = frag(Bh_s, wn + n*16 + lr, kc*4 + lg);
                if constexpr (WSPLIT)
                    bl[n] = frag(Bl_s, wn + n*16 + lr, kc*4 + lg);
            }
#pragma unroll
            for (int m = 0; m < 4; ++m)
#pragma unroll
                for (int n = 0; n < 4; ++n){
                    acc[m][n] = MFMA16(ah[m], bh[n], acc[m][n]);
                    if constexpr (WSPLIT)
                        acc[m][n] = MFMA16(ah[m], bl[n], acc[m][n]);
                    acc[m][n] = MFMA16(al[m], bh[n], acc[m][n]);
                }
        }
        __syncthreads();
    }

    const int sec = bcol >> 10;     // block-uniform: 0=q 1=k 2=v (QKV only)
#pragma unroll
    for (int m = 0; m < 4; ++m)
#pragma unroll
        for (int n = 0; n < 4; ++n){
            int row  = brow + wm + m*16 + lg*4;
            int gcol = bcol + wn + n*16 + lr;
            float bv = bias[gcol];
#pragma unroll
            for (int v = 0; v < 4; ++v){
                float val = acc[m][n][v] + bv;
                if constexpr (QKV){
                    int col1 = gcol & 1023;
                    size_t o = (size_t)(row + v)*DM + col1;
                    if (sec == 0){ bfpair p = split_bf(val); o0h[o] = p.hi; o0l[o] = p.lo; }
                    else if (sec == 1){ o1h[o] = f2bf(val); }
                    else { o2[o] = f2bf(val); }
                } else {
                    oproj[(size_t)(row + v)*DM + gcol] = val;
                }
            }
        }
}

// ---------------- prep kernels ----------------
__global__ __launch_bounds__(256)
void split_f32(const float* __restrict__ x, short* __restrict__ h,
               short* __restrict__ l, int n4)
{
    int i = blockIdx.x*256 + threadIdx.x;
    if (i >= n4) return;
    float4 v = *(const float4*)&x[(size_t)i*4];
    bfpair a = split_bf(v.x), b = split_bf(v.y), c = split_bf(v.z), d = split_bf(v.w);
    s16x4 hv, lv;
    hv.x = a.hi; hv.y = b.hi; hv.z = c.hi; hv.w = d.hi;
    lv.x = a.lo; lv.y = b.lo; lv.z = c.lo; lv.w = d.lo;
    *(s16x4*)&h[(size_t)i*4] = hv;
    *(s16x4*)&l[(size_t)i*4] = lv;
}

template<bool SPL>
__global__ __launch_bounds__(256)
void wtrans(const float* __restrict__ W, int N, short* __restrict__ Th,
            short* __restrict__ Tl)
{
    __shared__ float t[64][65];
    const int tid = threadIdx.x;
    const int tn = blockIdx.x*64, tk = blockIdx.y*64;
#pragma unroll
    for (int it = 0; it < 4; ++it){
        int idx = tid + it*256;
        int r = idx >> 4, c4 = (idx & 15)*4;
        float4 v = *(const float4*)&W[(size_t)(tk + r)*N + tn + c4];
        t[r][c4] = v.x; t[r][c4+1] = v.y; t[r][c4+2] = v.z; t[r][c4+3] = v.w;
    }
    __syncthreads();
#pragma unroll
    for (int it = 0; it < 4; ++it){
        int idx = tid + it*256;
        int n = idx >> 4, c4 = (idx & 15)*4;
        s16x4 hv, lv;
#pragma unroll
        for (int j = 0; j < 4; ++j){
            bfpair p = split_bf(t[c4+j][n]);
            hv[j] = p.hi; lv[j] = p.lo;
        }
        *(s16x4*)&Th[(size_t)(tn + n)*DM + tk + c4] = hv;
        if constexpr (SPL) *(s16x4*)&Tl[(size_t)(tn + n)*DM + tk + c4] = lv;
    }
}

__global__ __launch_bounds__(256)
void vtrans(const short* __restrict__ Vb, short* __restrict__ Vt)
{
    __shared__ short t[64][66];
    const int tid = threadIdx.x;
    const int td = blockIdx.x*64, ts = blockIdx.y*64;
#pragma unroll
    for (int it = 0; it < 4; ++it){
        int idx = tid + it*256;
        int r = idx >> 4, c4 = (idx & 15)*4;
        s16x4 v = *(const s16x4*)&Vb[(size_t)(ts + r)*DM + td + c4];
        t[r][c4] = v.x; t[r][c4+1] = v.y; t[r][c4+2] = v.z; t[r][c4+3] = v.w;
    }
    __syncthreads();
#pragma unroll
    for (int it = 0; it < 4; ++it){
        int idx = tid + it*256;
        int n = idx >> 4, c4 = (idx & 15)*4;
        s16x4 o;
#pragma unroll
        for (int j = 0; j < 4; ++j) o[j] = t[c4+j][n];
        *(s16x4*)&Vt[(size_t)(td + n)*S_LEN + ts + c4] = o;
    }
}

// per-64-key-block partial sums of V, then per-head suffix sums
__global__ __launch_bounds__(64)
void sv_partial(const short* __restrict__ Vb, float* __restrict__ PB)
{
    int b = blockIdx.x, h = blockIdx.y, d = threadIdx.x;
    float s = 0.f;
#pragma unroll 8
    for (int k = 0; k < 64; ++k)
        s += bf2f(Vb[(size_t)(b*64 + k)*DM + h*HD + d]);
    PB[((size_t)h*32 + b)*64 + d] = s;
}
__global__ __launch_bounds__(64)
void sv_suffix(const float* __restrict__ PB, float* __restrict__ SSV)
{
    int h = blockIdx.x, d = threadIdx.x;
    float s = 0.f;
    SSV[((size_t)h*33 + 32)*64 + d] = 0.f;
    for (int b = 31; b >= 0; --b){
        s += PB[((size_t)h*32 + b)*64 + d];
        SSV[((size_t)h*33 + b)*64 + d] = s;
    }
}

// ---------------- Flash attention, 1 wave per 16 q-rows ----------------
__global__ __launch_bounds__(64)
void attn_fwd(const short* __restrict__ Qh, const short* __restrict__ Ql,
              const short* __restrict__ Kh, const short* __restrict__ Vt,
              const float* __restrict__ SSV,
              short* __restrict__ Oh, short* __restrict__ Ol)
{
    __shared__ __align__(16) short Ps[16*72];

    const int id = blockIdx.x;                 // 0..2047
    const int h  = (id & 7) + 8*((id >> 3) & 1);   // heads pinned per XCD
    const int qt = 127 - (id >> 4);            // descending diag = LPT order
    const int diag = qt >> 2;                  // last kv-block with live keys

    const int lane = threadIdx.x, lr = lane & 15, lg = lane >> 4;
    const int qrow = qt*16 + lg*4;

    // Q fragments direct from global (used from registers for all iterations)
    const short* qbh = Qh + (size_t)(qt*16)*DM + h*HD;
    const short* qbl = Ql + (size_t)(qt*16)*DM + h*HD;
    s16x8 aqh[2], aql[2];
#pragma unroll
    for (int kc = 0; kc < 2; ++kc){
        aqh[kc] = *(const s16x8*)&qbh[(size_t)lr*DM + kc*32 + lg*8];
        aql[kc] = *(const s16x8*)&qbl[(size_t)lr*DM + kc*32 + lg*8];
    }

    float m_run[4], l_run[4];
    f32x4 acc_o[4];
#pragma unroll
    for (int v = 0; v < 4; ++v){ m_run[v] = -1e30f; l_run[v] = 0.f; }
#pragma unroll
    for (int n = 0; n < 4; ++n) acc_o[n] = (f32x4){0.f,0.f,0.f,0.f};

    const short* kb0 = Kh + (size_t)h*HD;
    const short* vb0 = Vt + (size_t)(h*HD)*S_LEN;

    for (int kvb = 0; kvb <= diag; ++kvb){
        // K fragments (bf16 hi only)
        const short* kb = kb0 + (size_t)(kvb*64)*DM;
        s16x8 bk[2][4];
#pragma unroll
        for (int kc = 0; kc < 2; ++kc)
#pragma unroll
            for (int n = 0; n < 4; ++n)
                bk[kc][n] = *(const s16x8*)&kb[(size_t)(n*16 + lr)*DM + kc*32 + lg*8];

        f32x4 sc[4];
#pragma unroll
        for (int n = 0; n < 4; ++n) sc[n] = (f32x4){0.f,0.f,0.f,0.f};
#pragma unroll
        for (int kc = 0; kc < 2; ++kc)
#pragma unroll
            for (int n = 0; n < 4; ++n){
                sc[n] = MFMA16(aqh[kc], bk[kc][n], sc[n]);
                sc[n] = MFMA16(aql[kc], bk[kc][n], sc[n]);
            }

        // issue V fragment loads early; latency hides under softmax VALU
        const short* vb = vb0 + kvb*64;
        s16x8 bv0[4], bv1[4];
#pragma unroll
        for (int n = 0; n < 4; ++n){
            bv0[n] = *(const s16x8*)&vb[(size_t)(16*n + lr)*S_LEN + lg*8];
            bv1[n] = *(const s16x8*)&vb[(size_t)(16*n + lr)*S_LEN + 32 + lg*8];
        }

        // soft-threshold (+ causal mask only in the diagonal block)
        float p[4][4], tmax[4];
#pragma unroll
        for (int v = 0; v < 4; ++v) tmax[v] = -1e30f;
        if (kvb == diag){
#pragma unroll
            for (int n = 0; n < 4; ++n){
                int key = kvb*64 + n*16 + lr;
#pragma unroll
                for (int v = 0; v < 4; ++v){
                    float w;
                    if (key > qrow + v) w = CMASK;
                    else {
                        float sv = sc[n][v];
                        float sig = 1.f / (1.f + __expf(-SLOPE*sv));
                        w = CMASK + (sv - CMASK)*sig;
                    }
                    p[n][v] = w;
                    tmax[v] = fmaxf(tmax[v], w);
                }
            }
        } else {
#pragma unroll
            for (int n = 0; n < 4; ++n)
#pragma unroll
                for (int v = 0; v < 4; ++v){
                    float sv = sc[n][v];
                    float sig = 1.f / (1.f + __expf(-SLOPE*sv));
                    float w = CMASK + (sv - CMASK)*sig;
                    p[n][v] = w;
                    tmax[v] = fmaxf(tmax[v], w);
                }
        }
#pragma unroll
        for (int v = 0; v < 4; ++v)
#pragma unroll
            for (int msk = 1; msk < 16; msk <<= 1)
                tmax[v] = fmaxf(tmax[v], __shfl_xor(tmax[v], msk, 64));

        float scale[4], rsum[4];
#pragma unroll
        for (int v = 0; v < 4; ++v){
            float mn = fmaxf(m_run[v], tmax[v]);
            scale[v] = __expf(m_run[v] - mn);
            m_run[v] = mn;
            rsum[v] = 0.f;
        }
#pragma unroll
        for (int n = 0; n < 4; ++n)
#pragma unroll
            for (int v = 0; v < 4; ++v){
                float e = __expf(p[n][v] - m_run[v]);
                p[n][v] = e;
                rsum[v] += e;
            }
#pragma unroll
        for (int v = 0; v < 4; ++v){
#pragma unroll
            for (int msk = 1; msk < 16; msk <<= 1)
                rsum[v] += __shfl_xor(rsum[v], msk, 64);
            l_run[v] = l_run[v]*scale[v] + rsum[v];
        }
#pragma unroll
        for (int n = 0; n < 4; ++n)
#pragma unroll
            for (int v = 0; v < 4; ++v) acc_o[n][v] *= scale[v];

        // P (D-layout) -> LDS -> A-frag layout
#pragma unroll
        for (int n = 0; n < 4; ++n)
#pragma unroll
            for (int v = 0; v < 4; ++v)
                Ps[(lg*4 + v)*72 + 16*n + lr] = f2bf(p[n][v]);
        asm volatile("s_waitcnt lgkmcnt(0)" ::: "memory");

        s16x8 pa0 = *(const s16x8*)&Ps[lr*72 + lg*8];
        s16x8 pa1 = *(const s16x8*)&Ps[lr*72 + 32 + lg*8];
#pragma unroll
        for (int n = 0; n < 4; ++n){
            acc_o[n] = MFMA16(pa0, bv0[n], acc_o[n]);
            acc_o[n] = MFMA16(pa1, bv1[n], acc_o[n]);
        }
    }

    // analytic masked-future tail: every future key has weight exp(CMASK - m).
    // exp underflows to 0 exactly like the reference once m - CMASK > ~87.
    {
        const float* sv = SSV + ((size_t)h*33 + (diag + 1))*64;
        float F = (float)(S_LEN - 64*(diag + 1));
        float e[4];
#pragma unroll
        for (int v = 0; v < 4; ++v){
            e[v] = __expf(CMASK - m_run[v]);
            l_run[v] += e[v]*F;
        }
#pragma unroll
        for (int n = 0; n < 4; ++n){
            float svv = sv[16*n + lr];
#pragma unroll
            for (int v = 0; v < 4; ++v) acc_o[n][v] += e[v]*svv;
        }
    }

    // normalize + split-store bf16 hi/lo
#pragma unroll
    for (int n = 0; n < 4; ++n)
#pragma unroll
        for (int v = 0; v < 4; ++v){
            int row = qt*16 + lg*4 + v;
            int col = h*HD + 16*n + lr;
            bfpair p = split_bf(acc_o[n][v] / l_run[v]);
            Oh[(size_t)row*DM + col] = p.hi;
            Ol[(size_t)row*DM + col] = p.lo;
        }
}

extern "C" void kernel_launch(void* const* d_in, const int* in_sizes, int n_in,
                              void* d_out, int out_size, void* d_ws, size_t ws_size,
                              hipStream_t stream)
{
    (void)in_sizes; (void)n_in; (void)out_size; (void)ws_size;
    const float* hs   = (const float*)d_in[0];
    const float* wqkv = (const float*)d_in[1];
    const float* bqkv = (const float*)d_in[2];
    const float* wprj = (const float*)d_in[3];
    const float* bprj = (const float*)d_in[4];

    char* p = (char*)d_ws;                       // ~45.2 MiB used
    short* Ahg  = (short*)(p + (0ull  << 20));   // 4 MiB  (later: Oh)
    short* Alg  = (short*)(p + (4ull  << 20));   // 4 MiB  (later: Ol)
    short* WqTh = (short*)(p + (8ull  << 20));   // 6 MiB  (later: WprojT)
    short* WqTl = (short*)(p + (14ull << 20));   // 6 MiB
    short* Qhg  = (short*)(p + (20ull << 20));   // 4 MiB
    short* Qlg  = (short*)(p + (24ull << 20));
    short* Khg  = (short*)(p + (28ull << 20));
    short* Vbg  = (short*)(p + (32ull << 20));
    short* Vtg  = (short*)(p + (36ull << 20));
    float* PB   = (float*)(p + (40ull << 20));   // 128 KiB
    float* SSV  = (float*)(p + (41ull << 20));   // 132 KiB
    short* Oh = Ahg, * Ol = Alg;                 // reuse after GEMM1
    short* WpT = WqTh;                           // reuse after GEMM1

    split_f32<<<S_LEN*DM/4/256, 256, 0, stream>>>(hs, Ahg, Alg, S_LEN*DM/4);
    wtrans<true><<<dim3(NQKV/64, DM/64), 256, 0, stream>>>(wqkv, NQKV, WqTh, WqTl);

    gemm_kern<true, true><<<dim3(NQKV/128, S_LEN/128), 256, 0, stream>>>(
        Ahg, Alg, WqTh, WqTl, bqkv, Qhg, Qlg, Khg, Vbg, nullptr);

    wtrans<false><<<dim3(DM/64, DM/64), 256, 0, stream>>>(wprj, DM, WpT, nullptr);
    vtrans<<<dim3(DM/64, S_LEN/64), 256, 0, stream>>>(Vbg, Vtg);
    sv_partial<<<dim3(32, NH), 64, 0, stream>>>(Vbg, PB);
    sv_suffix<<<NH, 64, 0, stream>>>(PB, SSV);

    attn_fwd<<<2048, 64, 0, stream>>>(Qhg, Qlg, Khg, Vtg, SSV, Oh, Ol);

    gemm_kern<false, false><<<dim3(DM/128, S_LEN/128), 256, 0, stream>>>(
        Oh, Ol, WpT, nullptr, bprj, nullptr, nullptr, nullptr, nullptr,
        (float*)d_out);
}